// Round 3
// baseline (1217.950 us; speedup 1.0000x reference)
//
#include <hip/hip_runtime.h>
#include <hip/hip_bf16.h>

// QLinear int4-dequant GEMM: C[8192,11008] = X[8192,4096](fp32) @ deq(W)[4096,11008]
// v4: v3's staging/vmcnt structure kept verbatim; compute switched to
//     mfma_f32_32x32x16_bf16 (2382-2495 TF pipe vs 2075 for 16x16): per wave
//     4x2 frags of 32x32, 2 phases per K-tile (16 MFMA + 12 ds_read_b128 +
//     2 stage calls each), half the MFMA instructions and half the barriers.
// v3 post-mortem: MfmaUtil 45%, VALUBusy 17%, 0 bank conflicts, 746us = 48%
// of the 16x16-shape floor (356us). 32x32 floor is 296us.

#define K_DIM 4096
#define N_DIM 11008
#define M_DIM 8192
#define NTILE (K_DIM / 64)   // 64 K-tiles of BK=64

typedef unsigned short u16;
typedef __attribute__((ext_vector_type(8))) short short8;       // 8 x bf16 MFMA A/B frag
typedef __attribute__((ext_vector_type(4))) float f32x4;        // float4 loads
typedef __attribute__((ext_vector_type(16))) float f32x16;      // 32x32 MFMA C/D frag
typedef __attribute__((ext_vector_type(4))) unsigned int u32x4; // 16B store of 8 bf16

__device__ __forceinline__ unsigned cvt2(float a, float b) {
    __hip_bfloat162 h = __float22bfloat162_rn(make_float2(a, b));
    unsigned u;
    __builtin_memcpy(&u, &h, 4);
    return u;
}

#define GLOAD_LDS16(g, l)                                                 \
    __builtin_amdgcn_global_load_lds(                                     \
        (const __attribute__((address_space(1))) unsigned int*)(g),       \
        (__attribute__((address_space(3))) unsigned int*)(l), 16, 0, 0)

// ---------------------------------------------------------------------------
// Pre-pass 1: X fp32 -> bf16. 8 floats/thread, fully coalesced.
__global__ __launch_bounds__(256) void xcvt(const float* __restrict__ X,
                                            u16* __restrict__ Xb) {
    const size_t i = ((size_t)blockIdx.x * 256 + threadIdx.x) * 8;
    f32x4 a = *(const f32x4*)(X + i);
    f32x4 b = *(const f32x4*)(X + i + 4);
    u32x4 v;
    v[0] = cvt2(a[0], a[1]);
    v[1] = cvt2(a[2], a[3]);
    v[2] = cvt2(b[0], b[1]);
    v[3] = cvt2(b[2], b[3]);
    *(u32x4*)(Xb + i) = v;
}

// ---------------------------------------------------------------------------
// Pre-pass 2: W int4 -> bf16, layout Wt[n][k] (k-contiguous, GEMM B^T form).
__global__ __launch_bounds__(256) void wdeq(const int* __restrict__ Q,
                                            const float* __restrict__ SC,
                                            const float* __restrict__ ZP,
                                            u16* __restrict__ Wt) {
    const int t  = threadIdx.x;
    const int n  = blockIdx.x * 32 + (t >> 3);
    const int kw = blockIdx.y * 8 + (t & 7);
    const unsigned w = (unsigned)Q[(size_t)kw * N_DIM + n];
    const float sc  = SC[n];
    const float nzs = -ZP[n] * sc;  // exact affine: (float)nib * sc + nzs
    float f[8];
#pragma unroll
    for (int j = 0; j < 8; ++j)  // k = kw*8 + j, nibble j at bits [28-4j..31-4j]
        f[j] = fmaf((float)((w >> (28 - 4 * j)) & 15u), sc, nzs);
    u32x4 v;
    v[0] = cvt2(f[0], f[1]);
    v[1] = cvt2(f[2], f[3]);
    v[2] = cvt2(f[4], f[5]);
    v[3] = cvt2(f[6], f[7]);
    *(u32x4*)(Wt + (size_t)n * K_DIM + kw * 8) = v;
}

// ---------------------------------------------------------------------------
// Main GEMM: 256x256 tile, BK=64, 8 waves (2M x 4N), per-wave 128x64 output
// as 4x2 frags of mfma_f32_32x32x16_bf16. LDS: [buf][mat][kh] = 8 regions x
// 16 KiB (256 rows x 32 k), XOR-swizzled: LDS[row][u] holds global k-unit
// u ^ ((row>>1)&3)  (0-conflict, HW-verified rounds 1-2). 2 phases per K-tile
// (kh0, kh1); each phase stages 2 future regions; one vmcnt(4) per K-tile
// keeps the 2 newest regions in flight (never drained to 0 in steady state).
__global__ __launch_bounds__(512, 2) void qgemm_32(const u16* __restrict__ Ab,
                                                   const u16* __restrict__ Bt,
                                                   float* __restrict__ C) {
    __shared__ u16 lds[8 * 8192];   // 128 KiB

    const int tid  = threadIdx.x;
    const int lane = tid & 63;
    const int wave = tid >> 6;
    const int wm = wave >> 2;       // 0..1 (M half: 128 rows)
    const int wn = wave & 3;        // 0..3 (N quarter: 64 cols)

    // Bijective XCD swizzle: nwg = 43*32 = 1376 = 8*172
    const int bid = (int)blockIdx.x;
    const int swz = (bid & 7) * 172 + (bid >> 3);
    const int bx = swz % 43;
    const int by = swz / 43;
    const int m0 = by * 256;
    const int n0 = bx * 256;

    // Staging: linear LDS dest (16B-unit = tid), global source pre-swizzled:
    // row tid>>2, source k-unit (tid&3) ^ ((tid>>3)&3) == (tid&3) ^ ((row>>1)&3).
    const int srow = tid >> 2;
    const int sg   = (tid & 3) ^ ((tid >> 3) & 3);
    const u16* gA = Ab + (size_t)(m0 + srow) * K_DIM + sg * 8;
    const u16* gB = Bt + (size_t)(n0 + srow) * K_DIM + sg * 8;
    u16* ldst = &lds[tid * 8];

    auto stage = [&](int buf, int mat, int kh, int kt) {
        const u16* g = (mat ? gB : gA) + kt * 64 + kh * 32;
        u16* l = ldst + ((buf * 2 + mat) * 2 + kh) * 8192;
        GLOAD_LDS16(g, l);
        GLOAD_LDS16(g + (size_t)128 * K_DIM, l + 4096);  // rows 128..255
    };

    // 32x32x16 fragment mapping: A row = lane&31, k = (lane>>5)*8 + j;
    // B col = lane&31, same k. Read 8 consecutive k (one 16B unit) from the
    // swizzled region: unit = (2*s + hi) ^ sw, sw = ((lane&31)>>1)&3
    // (wm*128 / wn*64 / frag*32 row offsets are all 0 mod 4 after >>1).
    const int c31 = lane & 31;
    const int hi  = lane >> 5;
    const int sw  = (c31 >> 1) & 3;
    const int arow0 = (wm * 128 + c31) * 32;   // u16 offset of A row, +mi*32*32
    const int brow0 = (wn * 64 + c31) * 32;    // u16 offset of B row, +ni*32*32

    short8 af[2][4], bf[2][2];
    f32x16 acc[4][2] = {};   // [mi][ni]

    auto rdAB = [&](int buf, int kh) {
        const u16* pa = &lds[(buf * 4 + kh) * 8192];
        const u16* pb = &lds[(buf * 4 + 2 + kh) * 8192];
#pragma unroll
        for (int s = 0; s < 2; ++s) {
            const int uo = ((2 * s + hi) ^ sw) * 8;
#pragma unroll
            for (int mi = 0; mi < 4; ++mi)
                af[s][mi] = *(const short8*)(pa + arow0 + mi * 1024 + uo);
#pragma unroll
            for (int ni = 0; ni < 2; ++ni)
                bf[s][ni] = *(const short8*)(pb + brow0 + ni * 1024 + uo);
        }
    };
    auto mmac = [&]() {   // 16 MFMA: 4m x 2n x 2 k-steps
        __builtin_amdgcn_s_setprio(1);
#pragma unroll
        for (int s = 0; s < 2; ++s)
#pragma unroll
            for (int mi = 0; mi < 4; ++mi)
#pragma unroll
                for (int ni = 0; ni < 2; ++ni)
                    acc[mi][ni] = __builtin_amdgcn_mfma_f32_32x32x16_bf16(
                        af[s][mi], bf[s][ni], acc[mi][ni], 0, 0, 0);
        __builtin_amdgcn_s_setprio(0);
    };

    // Prologue: T=0 fully + T=1 kh0 (12 loads); vmcnt(4) leaves T=1 kh0 in flight.
    stage(0, 0, 0, 0); stage(0, 1, 0, 0); stage(0, 0, 1, 0); stage(0, 1, 1, 0);
    stage(1, 0, 0, 1); stage(1, 1, 0, 1);
    asm volatile("s_waitcnt vmcnt(4)" ::: "memory");
    __builtin_amdgcn_s_barrier();

    for (int T = 0; T < NTILE; ++T) {
        const int b = T & 1;
        const bool p1 = (T + 1 < NTILE);
        const bool p2 = (T + 2 < NTILE);

        // phase 0 (kh0): stage (T+1).kh1 -> other buf
        rdAB(b, 0);
        if (p1) { stage(b ^ 1, 0, 1, T + 1); stage(b ^ 1, 1, 1, T + 1); }
        __builtin_amdgcn_s_barrier();
        mmac();
        __builtin_amdgcn_s_barrier();

        // phase 1 (kh1): kh0 of this buf fully consumed -> stage (T+2).kh0;
        // counted wait: (T+1) complete, (T+2).kh0 (4 loads) stays in flight.
        rdAB(b, 1);
        if (p2) {
            stage(b, 0, 0, T + 2); stage(b, 1, 0, T + 2);
            asm volatile("s_waitcnt vmcnt(4)" ::: "memory");
        } else if (p1) {
            asm volatile("s_waitcnt vmcnt(0)" ::: "memory");
        }
        __builtin_amdgcn_s_barrier();
        mmac();
        __builtin_amdgcn_s_barrier();
    }

    // Epilogue: 32x32 C/D layout col=lane&31, row=(r&3)+8*(r>>2)+4*hi
    // (m74/m101-verified).
#pragma unroll
    for (int mi = 0; mi < 4; ++mi) {
#pragma unroll
        for (int ni = 0; ni < 2; ++ni) {
            const int rbase = m0 + wm * 128 + mi * 32 + 4 * hi;
            const int col   = n0 + wn * 64 + ni * 32 + c31;
#pragma unroll
            for (int r = 0; r < 16; ++r) {
                const int row = rbase + (r & 3) + 8 * (r >> 2);
                C[(size_t)row * N_DIM + col] = acc[mi][ni][r];
            }
        }
    }
}

// ---------------------------------------------------------------------------
// Fallback (round-0 verified fused kernel) for ws_size < 157.3 MB.
#define LDA 40
__global__ __launch_bounds__(256, 3) void qgemm_fused(
    const float* __restrict__ X, const int* __restrict__ Q,
    const float* __restrict__ SC, const float* __restrict__ ZP,
    float* __restrict__ C)
{
    __shared__ short As[128 * LDA];
    __shared__ short Bs[128 * LDA];

    const int tid  = threadIdx.x;
    const int lane = tid & 63;
    const int wave = tid >> 6;

    const int m0 = blockIdx.y * 128;
    const int n0 = blockIdx.x * 128;

    const int arow = tid >> 2;
    const int ak8  = (tid & 3) * 8;
    const float* xbase = X + (size_t)(m0 + arow) * K_DIM + ak8;

    const int bcol  = tid & 127;
    const int brow0 = tid >> 7;
    const int* qbase = Q + (size_t)brow0 * N_DIM + n0 + bcol;
    const float sc  = SC[n0 + bcol];
    const float nzs = -ZP[n0 + bcol] * sc;

    f32x4 areg[4];
    int   breg[2];

    auto load_tile = [&](int kt) {
        const float* p0 = xbase + kt;
        areg[0] = *(const f32x4*)(p0);
        areg[1] = *(const f32x4*)(p0 + 4);
        const float* p1 = p0 + (size_t)64 * K_DIM;
        areg[2] = *(const f32x4*)(p1);
        areg[3] = *(const f32x4*)(p1 + 4);
        const int* q0 = qbase + (size_t)(kt >> 3) * N_DIM;
        breg[0] = q0[0];
        breg[1] = q0[2 * N_DIM];
    };

    auto store_tile = [&]() {
        #pragma unroll
        for (int p = 0; p < 2; ++p) {
            u32x4 v;
            v[0] = cvt2(areg[2*p+0][0], areg[2*p+0][1]);
            v[1] = cvt2(areg[2*p+0][2], areg[2*p+0][3]);
            v[2] = cvt2(areg[2*p+1][0], areg[2*p+1][1]);
            v[3] = cvt2(areg[2*p+1][2], areg[2*p+1][3]);
            *(u32x4*)&As[(arow + p * 64) * LDA + ak8] = v;
        }
        #pragma unroll
        for (int r = 0; r < 2; ++r) {
            const unsigned w = (unsigned)breg[r];
            float f[8];
            #pragma unroll
            for (int j = 0; j < 8; ++j)
                f[j] = fmaf((float)((w >> (28 - 4*j)) & 15u), sc, nzs);
            u32x4 v;
            v[0] = cvt2(f[0], f[1]);
            v[1] = cvt2(f[2], f[3]);
            v[2] = cvt2(f[4], f[5]);
            v[3] = cvt2(f[6], f[7]);
            *(u32x4*)&Bs[bcol * LDA + (brow0 + 2*r) * 8] = v;
        }
    };

    f32x4 acc[4][4] = {};

    const int wm = (wave >> 1) * 64;
    const int wn = (wave & 1) * 64;
    const int fr = lane & 15;
    const int fq = lane >> 4;

    const short* Abase = &As[(wm + fr) * LDA + fq * 8];
    const short* Bbase = &Bs[(wn + fr) * LDA + fq * 8];

    load_tile(0);
    store_tile();
    __syncthreads();

    for (int kt = 0;;) {
        const int knext = kt + 32;
        const bool last = (knext >= K_DIM);
        if (!last) load_tile(knext);

        short8 af[4], bf[4];
        #pragma unroll
        for (int i = 0; i < 4; ++i) {
            af[i] = *(const short8*)(Abase + i * 16 * LDA);
            bf[i] = *(const short8*)(Bbase + i * 16 * LDA);
        }
        #pragma unroll
        for (int mi = 0; mi < 4; ++mi)
            #pragma unroll
            for (int ni = 0; ni < 4; ++ni)
                acc[mi][ni] = __builtin_amdgcn_mfma_f32_16x16x32_bf16(
                    af[mi], bf[ni], acc[mi][ni], 0, 0, 0);

        if (last) break;
        __syncthreads();
        store_tile();
        __syncthreads();
        kt = knext;
    }

    #pragma unroll
    for (int mi = 0; mi < 4; ++mi) {
        #pragma unroll
        for (int ni = 0; ni < 4; ++ni) {
            const int row = m0 + wm + mi * 16 + fq * 4;
            const int col = n0 + wn + ni * 16 + fr;
            float* cp = C + (size_t)row * N_DIM + col;
            #pragma unroll
            for (int r = 0; r < 4; ++r)
                cp[(size_t)r * N_DIM] = acc[mi][ni][r];
        }
    }
}

extern "C" void kernel_launch(void* const* d_in, const int* in_sizes, int n_in,
                              void* d_out, int out_size, void* d_ws, size_t ws_size,
                              hipStream_t stream) {
    const float* X  = (const float*)d_in[0];
    const int*   Q  = (const int*)d_in[1];
    const float* SC = (const float*)d_in[2];
    const float* ZP = (const float*)d_in[3];
    float*       C  = (float*)d_out;
    (void)in_sizes; (void)n_in; (void)out_size;

    const size_t xb_bytes = (size_t)M_DIM * K_DIM * 2;   // 67,108,864
    const size_t wt_bytes = (size_t)N_DIM * K_DIM * 2;   // 90,177,536

    if (ws_size >= xb_bytes + wt_bytes) {
        u16* Xb = (u16*)d_ws;
        u16* Wt = (u16*)((char*)d_ws + xb_bytes);
        xcvt<<<dim3(M_DIM * K_DIM / (256 * 8)), 256, 0, stream>>>(X, Xb);
        wdeq<<<dim3(N_DIM / 32, K_DIM / 64), 256, 0, stream>>>(Q, SC, ZP, Wt);
        qgemm_32<<<dim3((N_DIM / 256) * (M_DIM / 256)), 512, 0, stream>>>(Xb, Wt, C);
    } else {
        qgemm_fused<<<dim3(N_DIM / 128, M_DIM / 128), 256, 0, stream>>>(X, Q, SC, ZP, C);
    }
}